// Round 1
// baseline (373.320 us; speedup 1.0000x reference)
//
#include <hip/hip_runtime.h>
#include <stdint.h>

#define T_TOK   4096
#define D_MODEL 768
#define F_FF    3072
#define N_EXP   8
#define BM      128
#define MAX_TILES 40
#define MCAP    (MAX_TILES * BM)   // 5120 padded rows capacity

typedef __attribute__((ext_vector_type(4))) float  floatx4;
typedef __attribute__((ext_vector_type(8))) short  short8;

__device__ __forceinline__ unsigned short f2bf(float f) {
    union { float f; unsigned int u; } v; v.f = f;
    unsigned int u = v.u;
    unsigned int r = (u + 0x7FFFu + ((u >> 16) & 1u)) >> 16;  // RNE
    return (unsigned short)r;
}

// ---------------- router: one wave per token ----------------
__global__ __launch_bounds__(256) void router_kernel(
        const float* __restrict__ x, const float* __restrict__ wsw,
        const float* __restrict__ bsw, int* __restrict__ routes,
        int* __restrict__ cnt, float* __restrict__ rps) {
    __shared__ float srps[N_EXP];
    __shared__ int   scnt[N_EXP];
    int tid = threadIdx.x;
    if (tid < N_EXP) { srps[tid] = 0.f; scnt[tid] = 0; }
    __syncthreads();
    int wave = tid >> 6, l = tid & 63;
    int t = blockIdx.x * 4 + wave;
    const float* xr = x + (size_t)t * D_MODEL;
    double acc[N_EXP];
#pragma unroll
    for (int e = 0; e < N_EXP; e++) acc[e] = 0.0;
    for (int d = l; d < D_MODEL; d += 64) {
        float xv = xr[d];
        const float* wr = wsw + d * N_EXP;
#pragma unroll
        for (int e = 0; e < N_EXP; e++) acc[e] += (double)xv * (double)wr[e];
    }
#pragma unroll
    for (int off = 32; off > 0; off >>= 1) {
#pragma unroll
        for (int e = 0; e < N_EXP; e++) acc[e] += __shfl_xor(acc[e], off, 64);
    }
    if (l == 0) {
        float logit[N_EXP];
        float mx = -1e30f; int am = 0;
#pragma unroll
        for (int e = 0; e < N_EXP; e++) {
            logit[e] = (float)acc[e] + bsw[e];
            if (logit[e] > mx) { mx = logit[e]; am = e; }
        }
        float p[N_EXP]; float s = 0.f;
#pragma unroll
        for (int e = 0; e < N_EXP; e++) { p[e] = __expf(logit[e] - mx); s += p[e]; }
        float inv = 1.f / s;
        routes[t] = am;
        atomicAdd(&scnt[am], 1);
#pragma unroll
        for (int e = 0; e < N_EXP; e++) atomicAdd(&srps[e], p[e] * inv);
    }
    __syncthreads();
    if (tid < N_EXP) {
        atomicAdd(&cnt[tid], scnt[tid]);
        atomicAdd(&rps[tid], srps[tid]);
    }
}

// ---------------- plan: offsets, tile table, output tail ----------------
__global__ void plan_kernel(const int* __restrict__ cnt, const float* __restrict__ rps,
                            int* __restrict__ astart, int* __restrict__ cursor,
                            int* __restrict__ tile_e, int* __restrict__ tile_m0,
                            float* __restrict__ out_tail) {
    if (threadIdx.x == 0 && blockIdx.x == 0) {
        int a = 0, idx = 0;
        for (int e = 0; e < N_EXP; e++) {
            astart[e] = a; cursor[e] = a;
            int nt = (cnt[e] + BM - 1) / BM;
            for (int j = 0; j < nt; j++) { tile_e[idx] = e; tile_m0[idx] = a + j * BM; idx++; }
            a += nt * BM;
        }
        for (; idx < MAX_TILES; idx++) { tile_e[idx] = -1; tile_m0[idx] = 0; }
        for (int e = 0; e < N_EXP; e++) {
            out_tail[e] = (float)cnt[e];
            out_tail[N_EXP + e] = rps[e];
        }
        out_tail[2 * N_EXP] = 0.0f;   // n_dropped = 0 (int bits == float 0 bits)
    }
}

// ---------------- scatter tokens into expert-sorted perm ----------------
__global__ __launch_bounds__(256) void scatter_kernel(
        const int* __restrict__ routes, int* __restrict__ cursor, int* __restrict__ perm) {
    int t = blockIdx.x * blockDim.x + threadIdx.x;
    if (t < T_TOK) {
        int e = routes[t];
        int pos = atomicAdd(&cursor[e], 1);
        perm[pos] = t;
    }
}

// ---------------- gather + cast x rows to bf16 (pad rows -> 0) ----------------
__global__ __launch_bounds__(256) void gather_kernel(
        const float* __restrict__ x, const int* __restrict__ perm,
        unsigned short* __restrict__ Xs) {
    int m = blockIdx.x;
    int t = perm[m];
    unsigned short* dst = Xs + (size_t)m * D_MODEL;
    if (t >= 0) {
        const float* src = x + (size_t)t * D_MODEL;
        for (int i = threadIdx.x; i < D_MODEL; i += 256) dst[i] = f2bf(src[i]);
    } else {
        for (int i = threadIdx.x; i < D_MODEL; i += 256) dst[i] = 0;
    }
}

// ---------------- transpose + cast fp32 [R][C] -> bf16 [C][R], per expert ----------------
__global__ __launch_bounds__(256) void transpose_cast_kernel(
        const float* __restrict__ src, unsigned short* __restrict__ dst, int R, int C) {
    __shared__ float tile[64][65];
    int e = blockIdx.z;
    const float* s = src + (size_t)e * R * C;
    unsigned short* d = dst + (size_t)e * R * C;
    int tx = threadIdx.x & 63;
    int ty = threadIdx.x >> 6;            // 0..3
    int c0 = blockIdx.x * 64, r0 = blockIdx.y * 64;
#pragma unroll
    for (int k = 0; k < 16; k++) {
        int r = ty + k * 4;
        tile[r][tx] = s[(size_t)(r0 + r) * C + (c0 + tx)];
    }
    __syncthreads();
#pragma unroll
    for (int k = 0; k < 16; k++) {
        int c = ty + k * 4;
        ushort2 v;
        v.x = f2bf(tile[tx * 2][c]);
        v.y = f2bf(tile[tx * 2 + 1][c]);
        *(ushort2*)(&d[(size_t)(c0 + c) * R + (r0 + tx * 2)]) = v;
    }
}

// ---------------- 128x128x32 bf16 MFMA GEMM, B^T input, m97-style staging ----------------
// A: [Mcap][K] bf16 row-major (k contiguous).  Bt: per-expert [N][K] bf16 (k contiguous).
// RELU_BF16: C = relu(A*B) -> bf16 Obf[M][N].  else: fp32 scatter rows via perm -> Of32.
template <int K, int N, bool RELU_BF16>
__global__ __launch_bounds__(256) void gemm_bt_kernel(
        const unsigned short* __restrict__ A, const unsigned short* __restrict__ Bt,
        const int* __restrict__ tile_e, const int* __restrict__ tile_m0,
        const int* __restrict__ perm,
        unsigned short* __restrict__ Obf, float* __restrict__ Of32) {
    int e = tile_e[blockIdx.y];
    if (e < 0) return;
    int m0 = tile_m0[blockIdx.y];
    int n0 = blockIdx.x * 128;
    const unsigned short* Be = Bt + (size_t)e * N * K;

    __shared__ __align__(16) unsigned short ldsA[128 * 32];
    __shared__ __align__(16) unsigned short ldsB[128 * 32];

    int tid = threadIdx.x;
    int w = tid >> 6, l = tid & 63;
    int wm = w & 1, wn = w >> 1;
    int quad = l >> 4, l15 = l & 15;

    floatx4 zero = {0.f, 0.f, 0.f, 0.f};
    floatx4 acc[4][4];
#pragma unroll
    for (int i = 0; i < 4; i++)
#pragma unroll
        for (int j = 0; j < 4; j++) acc[i][j] = zero;

    // staging: each wave covers 16 rows (64B each) per instruction, 2 instrs per matrix
    int r0 = w * 16 + (l >> 2);
    int cb = (l & 3) * 16;                       // byte offset within 64B tile-row
    const char* gA = (const char*)(A + (size_t)(m0 + r0) * K) + cb;
    const char* gB = (const char*)(Be + (size_t)(n0 + r0) * K) + cb;
    char* lA = (char*)ldsA + w * 1024;           // wave-uniform LDS base
    char* lB = (char*)ldsB + w * 1024;
    const size_t rowskip = (size_t)64 * K * 2;   // +64 rows, bytes

#pragma unroll 1
    for (int kc = 0; kc < K; kc += 32) {
        const char* ga = gA + kc * 2;
        const char* gb = gB + kc * 2;
        __builtin_amdgcn_global_load_lds((const __attribute__((address_space(1))) unsigned int*)ga,
                                         (__attribute__((address_space(3))) unsigned int*)lA, 16, 0, 0);
        __builtin_amdgcn_global_load_lds((const __attribute__((address_space(1))) unsigned int*)(ga + rowskip),
                                         (__attribute__((address_space(3))) unsigned int*)(lA + 4096), 16, 0, 0);
        __builtin_amdgcn_global_load_lds((const __attribute__((address_space(1))) unsigned int*)gb,
                                         (__attribute__((address_space(3))) unsigned int*)lB, 16, 0, 0);
        __builtin_amdgcn_global_load_lds((const __attribute__((address_space(1))) unsigned int*)(gb + rowskip),
                                         (__attribute__((address_space(3))) unsigned int*)(lB + 4096), 16, 0, 0);
        __syncthreads();

        short8 af[4], bf[4];
#pragma unroll
        for (int i = 0; i < 4; i++)
            af[i] = *(const short8*)(ldsA + (wm * 64 + i * 16 + l15) * 32 + quad * 8);
#pragma unroll
        for (int j = 0; j < 4; j++)
            bf[j] = *(const short8*)(ldsB + (wn * 64 + j * 16 + l15) * 32 + quad * 8);
#pragma unroll
        for (int i = 0; i < 4; i++)
#pragma unroll
            for (int j = 0; j < 4; j++)
                acc[i][j] = __builtin_amdgcn_mfma_f32_16x16x32_bf16(af[i], bf[j], acc[i][j], 0, 0, 0);
        __syncthreads();
    }

    if (RELU_BF16) {
#pragma unroll
        for (int i = 0; i < 4; i++) {
#pragma unroll
            for (int r = 0; r < 4; r++) {
                int row = m0 + wm * 64 + i * 16 + quad * 4 + r;
                size_t base = (size_t)row * N + n0 + wn * 64 + l15;
#pragma unroll
                for (int j = 0; j < 4; j++) {
                    float v = acc[i][j][r];
                    v = v > 0.f ? v : 0.f;
                    Obf[base + j * 16] = f2bf(v);
                }
            }
        }
    } else {
#pragma unroll
        for (int i = 0; i < 4; i++) {
#pragma unroll
            for (int r = 0; r < 4; r++) {
                int row = m0 + wm * 64 + i * 16 + quad * 4 + r;
                int t = perm[row];
                if (t < 0) continue;
                size_t base = (size_t)t * N + n0 + wn * 64 + l15;
#pragma unroll
                for (int j = 0; j < 4; j++) Of32[base + j * 16] = acc[i][j][r];
            }
        }
    }
}

extern "C" void kernel_launch(void* const* d_in, const int* in_sizes, int n_in,
                              void* d_out, int out_size, void* d_ws, size_t ws_size,
                              hipStream_t stream) {
    const float* x   = (const float*)d_in[0];
    const float* wsw = (const float*)d_in[1];
    const float* bsw = (const float*)d_in[2];
    const float* wi  = (const float*)d_in[3];
    const float* wo  = (const float*)d_in[4];
    float* out = (float*)d_out;

    char* ws = (char*)d_ws;
    int*   cnt     = (int*)(ws + 0);      // 8 ints
    float* rps     = (float*)(ws + 64);   // 8 floats
    int*   cursor  = (int*)(ws + 128);
    int*   astart  = (int*)(ws + 192);
    int*   tile_e  = (int*)(ws + 256);    // 40 ints
    int*   tile_m0 = (int*)(ws + 512);    // 40 ints
    int*   perm    = (int*)(ws + 1024);                 // MCAP ints -> ends 21504
    int*   routes  = (int*)(ws + 1024 + MCAP * 4);      // 4096 ints -> ends 37888
    unsigned short* Xs = (unsigned short*)(ws + 37888);             // 5120*768*2  = 7,864,320
    unsigned short* Y1 = (unsigned short*)(ws + 7902208);           // 5120*3072*2 = 31,457,280
    unsigned short* Wt = (unsigned short*)(ws + 39359488);          // 8*3072*768*2 = 37,748,736 (ends ~77.1MB)

    hipMemsetAsync(ws, 0, 1024, stream);
    hipMemsetAsync(ws + 1024, 0xFF, MCAP * 4, stream);   // perm = -1

    router_kernel<<<T_TOK / 4, 256, 0, stream>>>(x, wsw, bsw, routes, cnt, rps);
    plan_kernel<<<1, 64, 0, stream>>>(cnt, rps, astart, cursor, tile_e, tile_m0,
                                      out + (size_t)T_TOK * D_MODEL);
    scatter_kernel<<<(T_TOK + 255) / 256, 256, 0, stream>>>(routes, cursor, perm);
    gather_kernel<<<MCAP, 256, 0, stream>>>(x, perm, Xs);

    // wi [E][D][F] -> Wt [E][F][D]
    transpose_cast_kernel<<<dim3(F_FF / 64, D_MODEL / 64, N_EXP), 256, 0, stream>>>(wi, Wt, D_MODEL, F_FF);
    gemm_bt_kernel<D_MODEL, F_FF, true><<<dim3(F_FF / 128, MAX_TILES), 256, 0, stream>>>(
        Xs, Wt, tile_e, tile_m0, perm, Y1, nullptr);

    // wo [E][F][D] -> Wt [E][D][F]
    transpose_cast_kernel<<<dim3(D_MODEL / 64, F_FF / 64, N_EXP), 256, 0, stream>>>(wo, Wt, F_FF, D_MODEL);
    gemm_bt_kernel<F_FF, D_MODEL, false><<<dim3(D_MODEL / 128, MAX_TILES), 256, 0, stream>>>(
        Y1, Wt, tile_e, tile_m0, perm, nullptr, out);
}